// Round 5
// baseline (107.191 us; speedup 1.0000x reference)
//
#include <hip/hip_runtime.h>
#include <stdint.h>

typedef short short8 __attribute__((ext_vector_type(8)));
typedef float f32x4 __attribute__((ext_vector_type(4)));

#define AS1 __attribute__((address_space(1)))
#define AS3 __attribute__((address_space(3)))

__device__ __forceinline__ void gl_lds16(const void* g, void* l) {
  __builtin_amdgcn_global_load_lds((const AS1 unsigned int*)g,
                                   (AS3 unsigned int*)l, 16, 0, 0);
}

__device__ __forceinline__ unsigned short f2bf(float f) {
  union { float f; unsigned int u; } v; v.f = f;
  return (unsigned short)((v.u + (((v.u >> 16) & 1u) + 0x7fffu)) >> 16);
}

// ---------------------------------------------------------------------------
// Pre-pass 1: x [16][256][64][64] fp32 NCHW -> x_t [16][64][64][256] bf16 NHWC
// ---------------------------------------------------------------------------
__global__ __launch_bounds__(256) void xpose_kernel(const float* __restrict__ x,
                                                    unsigned short* __restrict__ xt) {
  __shared__ float tile[64][68];
  const int bid = blockIdx.x;
  const int cchunk = bid & 3;
  const int y = (bid >> 2) & 63;
  const int b = bid >> 8;
  const int t = threadIdx.x;
  const int ci0 = cchunk * 64;

  const int cc = t >> 2;
  const int xo = (t & 3) * 16;
  const float* src = x + (((size_t)(b * 256 + ci0 + cc) * 64 + y) * 64 + xo);
  float4 v0 = ((const float4*)src)[0];
  float4 v1 = ((const float4*)src)[1];
  float4 v2 = ((const float4*)src)[2];
  float4 v3 = ((const float4*)src)[3];
  *(float4*)&tile[cc][xo + 0]  = v0;
  *(float4*)&tile[cc][xo + 4]  = v1;
  *(float4*)&tile[cc][xo + 8]  = v2;
  *(float4*)&tile[cc][xo + 12] = v3;
  __syncthreads();

  const int xpos = t >> 2;
  const int ccg = (t & 3) * 16;
  unsigned int pk[8];
#pragma unroll
  for (int e = 0; e < 8; ++e) {
    unsigned int lo = f2bf(tile[ccg + 2 * e][xpos]);
    unsigned int hi = f2bf(tile[ccg + 2 * e + 1][xpos]);
    pk[e] = lo | (hi << 16);
  }
  unsigned short* dst = xt + ((size_t)(b * 4096 + y * 64 + xpos) * 256 + ci0 + ccg);
  uint4 w0; w0.x = pk[0]; w0.y = pk[1]; w0.z = pk[2]; w0.w = pk[3];
  uint4 w1; w1.x = pk[4]; w1.y = pk[5]; w1.z = pk[6]; w1.w = pk[7];
  ((uint4*)dst)[0] = w0;
  ((uint4*)dst)[1] = w1;
}

// ---------------------------------------------------------------------------
// Pre-pass 2: w [256co][256ci][3][3] fp32 -> w_r [9 tap][256co][256ci] bf16
// ---------------------------------------------------------------------------
__global__ __launch_bounds__(256) void wpack_kernel(const float* __restrict__ w,
                                                    unsigned short* __restrict__ wrp) {
  const int idx = blockIdx.x * 256 + threadIdx.x;
  const int ci = idx & 255;
  const int co = (idx >> 8) & 255;
  const int p = idx >> 16;
  wrp[idx] = f2bf(w[(size_t)(co * 256 + ci) * 9 + p]);
}

// ---------------------------------------------------------------------------
// Main: implicit-GEMM conv. 128co x 256px tile, 512 thr / 8 waves (2co x 4px),
// 2 blocks/CU for cross-block DS<->MFMA overlap (m114/m97 mechanism).
// Ring-3 LDS (3 x 24 KB), 1 barrier + counted vmcnt(3) per K-tile,
// T2 XOR swizzle (verified conflict-free), T5 setprio.
// ---------------------------------------------------------------------------
__global__ __launch_bounds__(512, 4) void conv_mfma2(
    const unsigned short* __restrict__ xt,
    const unsigned short* __restrict__ wrp,
    const float* __restrict__ bias,
    float* __restrict__ out) {
  __shared__ unsigned short lds[3 * 12288];  // 3 bufs x (A 8KB + B 16KB) = 72 KiB

  const int tid = threadIdx.x;
  const int lane = tid & 63;
  const int wv = tid >> 6;
  const int wc = wv & 1;         // co half within block's 128 (0..1)
  const int wp = wv >> 1;        // px quarter (0..3)
  const int bid = blockIdx.x;    // [cohalf 1b][b 4b][ohtile 4b]
  const int cohalf = bid >> 8;   // co-half high bit: pair blocks share XCD (bid%8 equal)
  const int b = (bid >> 4) & 15;
  const int oh0 = (bid & 15) * 4;
  const int co0 = cohalf * 128;

  // ---- staging statics (linear LDS dest, inverse-swizzled global src) ----
  const int l2 = lane >> 2;                   // 0..15
  const int l3 = lane & 3;
  const int rA = wv * 16 + l2;                // A row 0..127
  const int slA = l3 ^ ((rA >> 1) & 3);
  const unsigned short* gA = wrp + (size_t)(co0 + rA) * 256 + slA * 8;
  const unsigned short* gB[2];
#pragma unroll
  for (int i = 0; i < 2; ++i) {
    const int r = wv * 32 + i * 16 + l2;      // B row (= px) 0..255
    const int sl = l3 ^ ((r >> 1) & 3);
    const int y = min(oh0 + (r >> 6), 61);    // clamp pad rows
    const int xc = min(r & 63, 61);           // clamp pad cols
    gB[i] = xt + ((size_t)(b * 64 + y) * 64 + xc) * 256 + sl * 8;
  }
  const unsigned ldsA  = wv * 512;            // ushort offsets within buf
  const unsigned ldsB0 = 4096 + wv * 1024;
  const unsigned ldsB1 = 4096 + wv * 1024 + 512;

  // ---- fragment read offsets (swizzled, ushorts within buf) ----
  int aoff[4], boff[4];
#pragma unroll
  for (int m = 0; m < 4; ++m) {
    const int row = wc * 64 + m * 16 + (lane & 15);
    const int s = (lane >> 4) ^ ((row >> 1) & 3);
    aoff[m] = row * 32 + s * 8;
  }
#pragma unroll
  for (int n = 0; n < 4; ++n) {
    const int row = wp * 64 + n * 16 + (lane & 15);
    const int s = (lane >> 4) ^ ((row >> 1) & 3);
    boff[n] = 4096 + row * 32 + s * 8;
  }

  auto stage = [&](int kt) {
    const int tap = kt >> 3, chunk = (kt & 7) * 32;
    const int kh = (tap * 11) >> 5, kw = tap - kh * 3;
    unsigned short* base = lds + (kt % 3) * 12288;
    gl_lds16(gA + tap * 65536 + chunk, base + ldsA);
    const int Boff = (kh * 64 + kw) * 256 + chunk;
    gl_lds16(gB[0] + Boff, base + ldsB0);
    gl_lds16(gB[1] + Boff, base + ldsB1);
  };

  f32x4 acc[4][4] = {};

  // prologue: stage tiles 0,1 (lookahead 2); drain tile 0, keep tile 1 in flight
  stage(0);
  stage(1);
  asm volatile("s_waitcnt vmcnt(3)" ::: "memory");
  __builtin_amdgcn_s_barrier();

  for (int kt = 0; kt < 72; ++kt) {
    unsigned short* buf = lds + (kt % 3) * 12288;
    short8 a[4], bb[4];
#pragma unroll
    for (int m = 0; m < 4; ++m) a[m] = *(const short8*)(buf + aoff[m]);
#pragma unroll
    for (int n = 0; n < 4; ++n) bb[n] = *(const short8*)(buf + boff[n]);
    if (kt < 70) stage(kt + 2);
    asm volatile("s_waitcnt lgkmcnt(0)" ::: "memory");
    __builtin_amdgcn_sched_barrier(0);
    __builtin_amdgcn_s_setprio(1);
#pragma unroll
    for (int m = 0; m < 4; ++m)
#pragma unroll
      for (int n = 0; n < 4; ++n)
        acc[m][n] = __builtin_amdgcn_mfma_f32_16x16x32_bf16(a[m], bb[n], acc[m][n], 0, 0, 0);
    __builtin_amdgcn_s_setprio(0);
    // counted drain: buf kt+1 must be landed before next iteration reads it
    if (kt < 70)       asm volatile("s_waitcnt vmcnt(3)" ::: "memory");
    else if (kt == 70) asm volatile("s_waitcnt vmcnt(0)" ::: "memory");
    __builtin_amdgcn_s_barrier();
  }

  // ---- epilogue: D col=lane&15 -> px, row=(lane>>4)*4+j -> co ----
  const int rb = (lane >> 4) * 4;
  const int colp = lane & 15;
#pragma unroll
  for (int m = 0; m < 4; ++m) {
    const int co = co0 + wc * 64 + m * 16 + rb;
    float bv[4];
#pragma unroll
    for (int j = 0; j < 4; ++j) bv[j] = bias[co + j];
#pragma unroll
    for (int n = 0; n < 4; ++n) {
      const int px = wp * 64 + n * 16 + colp;
      const int prow = px >> 6, ow = px & 63;
      const int oh = oh0 + prow;
      if (ow < 62 && oh < 62) {
#pragma unroll
        for (int j = 0; j < 4; ++j)
          out[((size_t)(b * 256 + co + j) * 62 + oh) * 62 + ow] = acc[m][n][j] + bv[j];
      }
    }
  }
}

// ---------------------------------------------------------------------------
// Fallback: naive fp32 direct conv (used only if d_ws is too small)
// ---------------------------------------------------------------------------
__global__ __launch_bounds__(256) void conv_naive(const float* __restrict__ x,
                                                  const float* __restrict__ wgt,
                                                  const float* __restrict__ bias,
                                                  float* __restrict__ out) {
  const size_t idx = (size_t)blockIdx.x * 256 + threadIdx.x;
  if (idx >= (size_t)16 * 256 * 62 * 62) return;
  const int ow = (int)(idx % 62);
  size_t r = idx / 62;
  const int oh = (int)(r % 62); r /= 62;
  const int co = (int)(r % 256);
  const int b = (int)(r / 256);
  float s = bias[co];
  for (int ci = 0; ci < 256; ++ci) {
    const float* xp = x + ((size_t)(b * 256 + ci) * 64 + oh) * 64 + ow;
    const float* wp = wgt + (size_t)(co * 256 + ci) * 9;
#pragma unroll
    for (int kh = 0; kh < 3; ++kh)
#pragma unroll
      for (int kw = 0; kw < 3; ++kw)
        s += xp[kh * 64 + kw] * wp[kh * 3 + kw];
  }
  out[idx] = s;
}

extern "C" void kernel_launch(void* const* d_in, const int* in_sizes, int n_in,
                              void* d_out, int out_size, void* d_ws, size_t ws_size,
                              hipStream_t stream) {
  const float* x = (const float*)d_in[0];
  const float* wgt = (const float*)d_in[1];
  const float* bias = (const float*)d_in[2];
  float* out = (float*)d_out;

  const size_t xt_elems = (size_t)16 * 64 * 64 * 256;
  const size_t wr_elems = (size_t)9 * 256 * 256;
  const size_t need = (xt_elems + wr_elems) * sizeof(unsigned short);

  if (ws_size < need) {
    conv_naive<<<61504, 256, 0, stream>>>(x, wgt, bias, out);
    return;
  }

  unsigned short* xt = (unsigned short*)d_ws;
  unsigned short* wrp = xt + xt_elems;

  xpose_kernel<<<4096, 256, 0, stream>>>(x, xt);
  wpack_kernel<<<2304, 256, 0, stream>>>(wgt, wrp);
  conv_mfma2<<<512, 512, 0, stream>>>(xt, wrp, bias, out);
}

// Round 7
// 97.526 us; speedup vs baseline: 1.0991x; 1.0991x over previous
//
#include <hip/hip_runtime.h>
#include <stdint.h>

typedef short short8 __attribute__((ext_vector_type(8)));
typedef float f32x4 __attribute__((ext_vector_type(4)));

#define AS1 __attribute__((address_space(1)))
#define AS3 __attribute__((address_space(3)))

__device__ __forceinline__ void gl_lds16(const void* g, void* l) {
  __builtin_amdgcn_global_load_lds((const AS1 unsigned int*)g,
                                   (AS3 unsigned int*)l, 16, 0, 0);
}

__device__ __forceinline__ unsigned short f2bf(float f) {
  union { float f; unsigned int u; } v; v.f = f;
  return (unsigned short)((v.u + (((v.u >> 16) & 1u) + 0x7fffu)) >> 16);
}

// ---------------------------------------------------------------------------
// Pre-pass 1: x [16][256][64][64] fp32 NCHW -> x_t [16][64][64][256] bf16 NHWC
// ---------------------------------------------------------------------------
__global__ __launch_bounds__(256) void xpose_kernel(const float* __restrict__ x,
                                                    unsigned short* __restrict__ xt) {
  __shared__ float tile[64][68];
  const int bid = blockIdx.x;
  const int cchunk = bid & 3;
  const int y = (bid >> 2) & 63;
  const int b = bid >> 8;
  const int t = threadIdx.x;
  const int ci0 = cchunk * 64;

  const int cc = t >> 2;
  const int xo = (t & 3) * 16;
  const float* src = x + (((size_t)(b * 256 + ci0 + cc) * 64 + y) * 64 + xo);
  float4 v0 = ((const float4*)src)[0];
  float4 v1 = ((const float4*)src)[1];
  float4 v2 = ((const float4*)src)[2];
  float4 v3 = ((const float4*)src)[3];
  *(float4*)&tile[cc][xo + 0]  = v0;
  *(float4*)&tile[cc][xo + 4]  = v1;
  *(float4*)&tile[cc][xo + 8]  = v2;
  *(float4*)&tile[cc][xo + 12] = v3;
  __syncthreads();

  const int xpos = t >> 2;
  const int ccg = (t & 3) * 16;
  unsigned int pk[8];
#pragma unroll
  for (int e = 0; e < 8; ++e) {
    unsigned int lo = f2bf(tile[ccg + 2 * e][xpos]);
    unsigned int hi = f2bf(tile[ccg + 2 * e + 1][xpos]);
    pk[e] = lo | (hi << 16);
  }
  unsigned short* dst = xt + ((size_t)(b * 4096 + y * 64 + xpos) * 256 + ci0 + ccg);
  uint4 w0; w0.x = pk[0]; w0.y = pk[1]; w0.z = pk[2]; w0.w = pk[3];
  uint4 w1; w1.x = pk[4]; w1.y = pk[5]; w1.z = pk[6]; w1.w = pk[7];
  ((uint4*)dst)[0] = w0;
  ((uint4*)dst)[1] = w1;
}

// ---------------------------------------------------------------------------
// Pre-pass 2: w [256co][256ci][3][3] fp32 -> w_r [9 tap][256co][256ci] bf16
// ---------------------------------------------------------------------------
__global__ __launch_bounds__(256) void wpack_kernel(const float* __restrict__ w,
                                                    unsigned short* __restrict__ wrp) {
  const int idx = blockIdx.x * 256 + threadIdx.x;
  const int ci = idx & 255;
  const int co = (idx >> 8) & 255;
  const int p = idx >> 16;
  wrp[idx] = f2bf(w[(size_t)(co * 256 + ci) * 9 + p]);
}

// ---------------------------------------------------------------------------
// Main: m201-style 8-phase implicit-GEMM conv.
// Tile 256co x 256px, 512 thr / 8 waves (wm 2 x wn 4), wave = 128co x 64px.
// 36 K-tiles of BK=64 (tap-aligned), 4 sub-phases per K-tile:
//   {ds_read subtile || 2x gl_lds -> bar -> lgkm0 -> 16 MFMA -> bar}
// double-buffered 2x64KB LDS, one counted vmcnt(2) per K-tile (never 0),
// T2 XOR swizzle both-sides, T5 setprio.
// ---------------------------------------------------------------------------
__global__ __launch_bounds__(512, 2) void conv_8ph(
    const unsigned short* __restrict__ xt,
    const unsigned short* __restrict__ wrp,
    const float* __restrict__ bias,
    float* __restrict__ out) {
  __shared__ unsigned short lds[2][32768];  // per buf: A [0,16384) co x k64, B [16384,32768) px x k64

  const int tid = threadIdx.x;
  const int lane = tid & 63;
  const int wv = tid >> 6;
  const int wm = wv >> 2;     // co half (128)
  const int wn = wv & 3;      // px quarter (64)
  const int bid = blockIdx.x;
  const int tile = (bid & 7) * 32 + (bid >> 3);  // XCD swizzle (256 % 8 == 0, bijective)
  const int b = tile >> 4;
  const int oh0 = (tile & 15) * 4;

  // ---- staging statics: chunk = 64 rows x k64 = 8KB = 1 gl_lds16/thread ----
  const int crow = tid >> 3;            // 0..63 row within chunk
  const int cslot = tid & 7;            // 16B slot
  const int sw = cslot ^ (crow & 7);    // inverse-swizzled source slot
  const unsigned short* gAbase = wrp + (size_t)crow * 256 + sw * 8;
  const unsigned short* gBbase[4];
#pragma unroll
  for (int cb = 0; cb < 4; ++cb) {
    const int y = min(oh0 + cb, 61);    // clamp pad rows (kh<=2 keeps y+kh<=63)
    const int x = min(crow, 61);        // clamp pad cols
    gBbase[cb] = xt + ((size_t)(b * 64 + y) * 64 + x) * 256 + sw * 8;
  }
  const unsigned dst_rc = crow * 64 + cslot * 8;  // + c*4096, elems

  // ---- fragment statics (swizzled read offsets) ----
  const int l15 = lane & 15;
  int s8[2];
  s8[0] = (((lane >> 4)) ^ (lane & 7)) * 8;
  s8[1] = (((lane >> 4) + 4) ^ (lane & 7)) * 8;
  int arow[8], brow[4];
#pragma unroll
  for (int a = 0; a < 8; ++a)
    arow[a] = (wm * 128 + (a >> 2) * 64 + (a & 3) * 16 + l15) * 64;
#pragma unroll
  for (int n = 0; n < 4; ++n)
    brow[n] = 16384 + (wn * 64 + n * 16 + l15) * 64;

  auto stageA = [&](int kt2, int c, unsigned short* bufp) {
    const int tap = kt2 >> 2, ci0 = (kt2 & 3) * 64;
    gl_lds16(gAbase + tap * 65536 + c * 16384 + ci0, bufp + c * 4096 + dst_rc);
  };
  auto stageB = [&](int kt2, int cb, unsigned short* bufp) {
    const int tap = kt2 >> 2, ci0 = (kt2 & 3) * 64;
    const int kh = (tap * 11) >> 5, kw = tap - kh * 3;
    gl_lds16(gBbase[cb] + (kh * 64 + kw) * 256 + ci0, bufp + (4 + cb) * 4096 + dst_rc);
  };

  f32x4 acc[8][4] = {};
  unsigned short* buf0 = &lds[0][0];
  unsigned short* buf1 = &lds[1][0];

  // prologue: buf0 full (kt=0) + buf1 chunks B4,B5 (kt=1); keep 2 in flight
  stageA(0, 0, buf0); stageA(0, 2, buf0); stageA(0, 1, buf0); stageA(0, 3, buf0);
  stageB(0, 2, buf0); stageB(0, 3, buf0); stageB(0, 0, buf0); stageB(0, 1, buf0);
  stageB(1, 0, buf1); stageB(1, 1, buf1);
  asm volatile("s_waitcnt vmcnt(2)" ::: "memory");
  __builtin_amdgcn_s_barrier();

  for (int kt = 0; kt < 36; ++kt) {
    unsigned short* buf = (kt & 1) ? buf1 : buf0;
    unsigned short* nbuf = (kt & 1) ? buf0 : buf1;
    short8 a0[4], a1[4], bb[4];

    // ---- p0: A(mh0,k0) + B(k0); stage A0,A2 of kt+1 -> nbuf ----
#pragma unroll
    for (int q = 0; q < 4; ++q) a0[q] = *(const short8*)(buf + arow[q] + s8[0]);
#pragma unroll
    for (int n = 0; n < 4; ++n) bb[n] = *(const short8*)(buf + brow[n] + s8[0]);
    if (kt < 35) { stageA(kt + 1, 0, nbuf); stageA(kt + 1, 2, nbuf); }
    __builtin_amdgcn_s_barrier();
    asm volatile("s_waitcnt lgkmcnt(0)" ::: "memory");
    __builtin_amdgcn_sched_barrier(0);
    __builtin_amdgcn_s_setprio(1);
#pragma unroll
    for (int q = 0; q < 4; ++q)
#pragma unroll
      for (int n = 0; n < 4; ++n)
        acc[q][n] = __builtin_amdgcn_mfma_f32_16x16x32_bf16(a0[q], bb[n], acc[q][n], 0, 0, 0);
    __builtin_amdgcn_s_setprio(0);
    __builtin_amdgcn_s_barrier();

    // ---- p1: A(mh1,k0), reuse B(k0) regs; stage A1,A3 of kt+1 ----
#pragma unroll
    for (int q = 0; q < 4; ++q) a1[q] = *(const short8*)(buf + arow[4 + q] + s8[0]);
    if (kt < 35) { stageA(kt + 1, 1, nbuf); stageA(kt + 1, 3, nbuf); }
    __builtin_amdgcn_s_barrier();
    asm volatile("s_waitcnt lgkmcnt(0)" ::: "memory");
    __builtin_amdgcn_sched_barrier(0);
    __builtin_amdgcn_s_setprio(1);
#pragma unroll
    for (int q = 0; q < 4; ++q)
#pragma unroll
      for (int n = 0; n < 4; ++n)
        acc[4 + q][n] = __builtin_amdgcn_mfma_f32_16x16x32_bf16(a1[q], bb[n], acc[4 + q][n], 0, 0, 0);
    __builtin_amdgcn_s_setprio(0);
    __builtin_amdgcn_s_barrier();

    // ---- p2: A(mh0,k1) + B(k1); stage B6,B7 of kt+1 ----
#pragma unroll
    for (int q = 0; q < 4; ++q) a0[q] = *(const short8*)(buf + arow[q] + s8[1]);
#pragma unroll
    for (int n = 0; n < 4; ++n) bb[n] = *(const short8*)(buf + brow[n] + s8[1]);
    if (kt < 35) { stageB(kt + 1, 2, nbuf); stageB(kt + 1, 3, nbuf); }
    __builtin_amdgcn_s_barrier();
    asm volatile("s_waitcnt lgkmcnt(0)" ::: "memory");
    __builtin_amdgcn_sched_barrier(0);
    __builtin_amdgcn_s_setprio(1);
#pragma unroll
    for (int q = 0; q < 4; ++q)
#pragma unroll
      for (int n = 0; n < 4; ++n)
        acc[q][n] = __builtin_amdgcn_mfma_f32_16x16x32_bf16(a0[q], bb[n], acc[q][n], 0, 0, 0);
    __builtin_amdgcn_s_setprio(0);
    __builtin_amdgcn_s_barrier();

    // ---- p3: A(mh1,k1); stage B4,B5 of kt+2 -> CURRENT buf (B region fully
    //      read at p0/p2; p2-end barrier + per-wave lgkm0 make this WAR-safe) ----
#pragma unroll
    for (int q = 0; q < 4; ++q) a1[q] = *(const short8*)(buf + arow[4 + q] + s8[1]);
    if (kt < 34) { stageB(kt + 2, 0, buf); stageB(kt + 2, 1, buf); }
    __builtin_amdgcn_s_barrier();
    asm volatile("s_waitcnt lgkmcnt(0)" ::: "memory");
    __builtin_amdgcn_sched_barrier(0);
    __builtin_amdgcn_s_setprio(1);
#pragma unroll
    for (int q = 0; q < 4; ++q)
#pragma unroll
      for (int n = 0; n < 4; ++n)
        acc[4 + q][n] = __builtin_amdgcn_mfma_f32_16x16x32_bf16(a1[q], bb[n], acc[4 + q][n], 0, 0, 0);
    __builtin_amdgcn_s_setprio(0);
    // counted drain: everything for kt+1 landed; only p3's 2 loads may remain
    if (kt < 34)       asm volatile("s_waitcnt vmcnt(2)" ::: "memory");
    else if (kt == 34) asm volatile("s_waitcnt vmcnt(0)" ::: "memory");
    __builtin_amdgcn_s_barrier();
  }

  // ---- epilogue: D col=lane&15 -> px, row=(lane>>4)*4+j -> co ----
  const int rb = (lane >> 4) * 4;
  const int colp = lane & 15;
#pragma unroll
  for (int a = 0; a < 8; ++a) {
    const int co = wm * 128 + (a >> 2) * 64 + (a & 3) * 16 + rb;
    float bv[4];
#pragma unroll
    for (int j = 0; j < 4; ++j) bv[j] = bias[co + j];
#pragma unroll
    for (int n = 0; n < 4; ++n) {
      const int px = wn * 64 + n * 16 + colp;
      const int prow = px >> 6, ow = px & 63;
      const int oh = oh0 + prow;
      if (ow < 62 && oh < 62) {
#pragma unroll
        for (int j = 0; j < 4; ++j)
          out[((size_t)(b * 256 + co + j) * 62 + oh) * 62 + ow] = acc[a][n][j] + bv[j];
      }
    }
  }
}

// ---------------------------------------------------------------------------
// Fallback: naive fp32 direct conv (used only if d_ws is too small)
// ---------------------------------------------------------------------------
__global__ __launch_bounds__(256) void conv_naive(const float* __restrict__ x,
                                                  const float* __restrict__ wgt,
                                                  const float* __restrict__ bias,
                                                  float* __restrict__ out) {
  const size_t idx = (size_t)blockIdx.x * 256 + threadIdx.x;
  if (idx >= (size_t)16 * 256 * 62 * 62) return;
  const int ow = (int)(idx % 62);
  size_t r = idx / 62;
  const int oh = (int)(r % 62); r /= 62;
  const int co = (int)(r % 256);
  const int b = (int)(r / 256);
  float s = bias[co];
  for (int ci = 0; ci < 256; ++ci) {
    const float* xp = x + ((size_t)(b * 256 + ci) * 64 + oh) * 64 + ow;
    const float* wp = wgt + (size_t)(co * 256 + ci) * 9;
#pragma unroll
    for (int kh = 0; kh < 3; ++kh)
#pragma unroll
      for (int kw = 0; kw < 3; ++kw)
        s += xp[kh * 64 + kw] * wp[kh * 3 + kw];
  }
  out[idx] = s;
}

extern "C" void kernel_launch(void* const* d_in, const int* in_sizes, int n_in,
                              void* d_out, int out_size, void* d_ws, size_t ws_size,
                              hipStream_t stream) {
  const float* x = (const float*)d_in[0];
  const float* wgt = (const float*)d_in[1];
  const float* bias = (const float*)d_in[2];
  float* out = (float*)d_out;

  const size_t xt_elems = (size_t)16 * 64 * 64 * 256;
  const size_t wr_elems = (size_t)9 * 256 * 256;
  const size_t need = (xt_elems + wr_elems) * sizeof(unsigned short);

  if (ws_size < need) {
    conv_naive<<<61504, 256, 0, stream>>>(x, wgt, bias, out);
    return;
  }

  unsigned short* xt = (unsigned short*)d_ws;
  unsigned short* wrp = xt + xt_elems;

  xpose_kernel<<<4096, 256, 0, stream>>>(x, xt);
  wpack_kernel<<<2304, 256, 0, stream>>>(wgt, wrp);
  conv_8ph<<<256, 512, 0, stream>>>(xt, wrp, bias, out);
}